// Round 6
// baseline (1791.678 us; speedup 1.0000x reference)
//
#include <hip/hip_runtime.h>
#include <math.h>

#define LQ 10105
#define BATCH 2
#define NLAYERS 6
#define NTOK (BATCH * LQ)   // 20210

typedef __attribute__((ext_vector_type(8))) short bf16x8;   // 8 bf16 (4 VGPRs)
typedef __attribute__((ext_vector_type(4))) float f32x4;

__device__ inline unsigned short f2bf_rne(float f) {
    unsigned u = __float_as_uint(f);
    unsigned r = u + 0x7fffu + ((u >> 16) & 1u);
    return (unsigned short)(r >> 16);
}
__device__ inline float bf2f(unsigned short h) {
    return __uint_as_float((unsigned)h << 16);
}
// truncation hi/lo split (matches R4/R5 GEMM A-split numerics)
__device__ inline void split2(float v, unsigned short& h, unsigned short& l) {
    h = (unsigned short)(__float_as_uint(v) >> 16);
    float r = v - bf2f(h);
    l = (unsigned short)(__float_as_uint(r) >> 16);
}

// async global->LDS, 16B per lane
__device__ inline void stage_plane(const unsigned short* __restrict__ gp,
                                   unsigned short* lp, int row0, int K, int kt,
                                   int tid)
{
    int r  = row0 + (tid >> 2);
    int kk = kt + (tid & 3) * 8;
    __builtin_amdgcn_global_load_lds(
        (const __attribute__((address_space(1))) void*)(gp + (size_t)r * K + kk),
        (__attribute__((address_space(3))) void*)(lp + tid * 8), 16, 0, 0);
    __builtin_amdgcn_global_load_lds(
        (const __attribute__((address_space(1))) void*)(gp + (size_t)(r + 64) * K + kk),
        (__attribute__((address_space(3))) void*)(lp + 2048 + tid * 8), 16, 0, 0);
}

// ---------------------------------------------------------------------------
// Flatten: (B,D,H,W) -> (B,HW,D) with LDS transpose; emits src f32, pos f32,
// src hi/lo planes, q=src+pos hi/lo planes.
// ---------------------------------------------------------------------------
__global__ __launch_bounds__(256)
void flatten_k(const float* __restrict__ src, const float* __restrict__ pos,
               const float* __restrict__ lvl, float* __restrict__ srcf,
               float* __restrict__ posf, unsigned short* __restrict__ sh,
               unsigned short* __restrict__ sl, unsigned short* __restrict__ qh,
               unsigned short* __restrict__ ql, int HW, int start)
{
    __shared__ float ts[64][65], tp[64][65];
    int hw0 = blockIdx.x * 64;
    int d0  = blockIdx.y * 64;
    int b   = blockIdx.z;
    int tid = threadIdx.x;
    int c = tid & 63, rg = tid >> 6;

    #pragma unroll 4
    for (int i = 0; i < 16; ++i) {
        int dl = rg * 16 + i;
        int hw = hw0 + c;
        float s = 0.f, p = 0.f;
        if (hw < HW) {
            s = src[(size_t)(b * 256 + d0 + dl) * HW + hw];
            p = pos[(size_t)(b * 256 + d0 + dl) * HW + hw];
        }
        ts[dl][c] = s;
        tp[dl][c] = p;
    }
    __syncthreads();
    float lv = lvl[d0 + c];
    #pragma unroll 4
    for (int i = 0; i < 16; ++i) {
        int hwl = rg * 16 + i;
        int hw = hw0 + hwl;
        if (hw >= HW) continue;
        float s = ts[c][hwl] + lv;
        float p = tp[c][hwl];
        size_t o = (size_t)(b * LQ + start + hw) * 256 + d0 + c;
        srcf[o] = s;
        posf[o] = p;
        unsigned short h, l;
        split2(s, h, l); sh[o] = h; sl[o] = l;
        float q = s + p;
        split2(q, h, l); qh[o] = h; ql[o] = l;
    }
}

// ---------------------------------------------------------------------------
// Weight transpose + bf16 hi/lo split: W[L][K][N] fp32 -> Th/Tl[L][N][K] bf16
// ---------------------------------------------------------------------------
__global__ __launch_bounds__(256)
void wsplit_k(const float* __restrict__ W, unsigned short* __restrict__ Th,
              unsigned short* __restrict__ Tl, int K, int N,
              long srcStride, long dstStride)
{
    __shared__ float t[32][33];
    int layer = blockIdx.z;
    int n0 = blockIdx.x * 32, k0 = blockIdx.y * 32;
    int tx = threadIdx.x & 31, ty = threadIdx.x >> 5;
    const float* Wsrc = W + (size_t)layer * srcStride;
    #pragma unroll
    for (int i = 0; i < 4; ++i)
        t[ty + i * 8][tx] = Wsrc[(size_t)(k0 + ty + i * 8) * N + n0 + tx];
    __syncthreads();
    unsigned short* th = Th + (size_t)layer * dstStride;
    unsigned short* tl = Tl + (size_t)layer * dstStride;
    #pragma unroll
    for (int i = 0; i < 4; ++i) {
        int n = n0 + ty + i * 8;
        float v = t[tx][ty + i * 8];
        unsigned short h = f2bf_rne(v);
        th[(size_t)n * K + k0 + tx] = h;
        tl[(size_t)n * K + k0 + tx] = f2bf_rne(v - bf2f(h));
    }
}

// combined bias [b_val | b_off | b_attn] -> 640 per layer
__global__ void boa_k(const float* __restrict__ b_val,
                      const float* __restrict__ b_off,
                      const float* __restrict__ b_attn, float* __restrict__ bo)
{
    int l = blockIdx.x, t = threadIdx.x;   // 640 threads
    float v;
    if (t < 256)      v = b_val[l * 256 + t];
    else if (t < 512) v = b_off[l * 256 + (t - 256)];
    else              v = b_attn[l * 128 + (t - 512)];
    bo[l * 640 + t] = v;
}

// ---------------------------------------------------------------------------
// Fused top GEMM: C[:,0:256]=src@w_val -> valb bf16; C[:,256:640]=(q)@[w_off|
// w_attn] -> oab f32. A planes selected per n-block. 3-pass split MFMA.
// 128x128x32 tile, 4 waves, global_load_lds staging, linear LDS.
// ---------------------------------------------------------------------------
__global__ __launch_bounds__(256)
void gemm_top(const unsigned short* __restrict__ Ash,
              const unsigned short* __restrict__ Asl,
              const unsigned short* __restrict__ Aqh,
              const unsigned short* __restrict__ Aql,
              const unsigned short* __restrict__ Bh,
              const unsigned short* __restrict__ Bl,
              const float* __restrict__ bias640,
              unsigned short* __restrict__ valb, float* __restrict__ oab, int M)
{
    constexpr int K = 256, NB = 5;
    __shared__ unsigned short sP[4 * 4096];  // Ah | Al | Bh | Bl
    unsigned short* sAh = sP;
    unsigned short* sAl = sP + 4096;
    unsigned short* sBh = sP + 8192;
    unsigned short* sBl = sP + 12288;

    const int nwg = gridDim.x, bid = blockIdx.x;
    const int q8 = nwg >> 3, r8 = nwg & 7, xcd = bid & 7;
    const int work = (xcd < r8 ? xcd * (q8 + 1) : r8 * (q8 + 1) + (xcd - r8) * q8)
                     + (bid >> 3);
    const int mblk = work / NB;
    const int nb = work - mblk * NB;
    const int m0 = mblk * 128, n0 = nb * 128;

    const unsigned short* Ah = (nb < 2) ? Ash : Aqh;
    const unsigned short* Al = (nb < 2) ? Asl : Aql;

    const int tid = threadIdx.x;
    const int w = tid >> 6, l = tid & 63;
    const int wm = (w >> 1) * 64, wn = (w & 1) * 64;
    const int lr = l & 15, kb = (l >> 4) * 8, rr = (l >> 4) * 4;

    f32x4 acc[4][4];
    #pragma unroll
    for (int i = 0; i < 4; ++i)
        #pragma unroll
        for (int j = 0; j < 4; ++j) acc[i][j] = (f32x4){0.f, 0.f, 0.f, 0.f};

    for (int kt = 0; kt < K; kt += 32) {
        stage_plane(Ah, sAh, m0, K, kt, tid);
        stage_plane(Al, sAl, m0, K, kt, tid);
        stage_plane(Bh, sBh, n0, K, kt, tid);
        stage_plane(Bl, sBl, n0, K, kt, tid);
        __syncthreads();
        bf16x8 fah[4], fal[4];
        #pragma unroll
        for (int mf = 0; mf < 4; ++mf) {
            int off = (wm + mf * 16 + lr) * 32 + kb;
            fah[mf] = *(const bf16x8*)&sAh[off];
            fal[mf] = *(const bf16x8*)&sAl[off];
        }
        #pragma unroll
        for (int nf = 0; nf < 4; ++nf) {
            int boff = (wn + nf * 16 + lr) * 32 + kb;
            bf16x8 fbh = *(const bf16x8*)&sBh[boff];
            bf16x8 fbl = *(const bf16x8*)&sBl[boff];
            #pragma unroll
            for (int mf = 0; mf < 4; ++mf) {
                f32x4 c = acc[mf][nf];
                c = __builtin_amdgcn_mfma_f32_16x16x32_bf16(fah[mf], fbh, c, 0, 0, 0);
                c = __builtin_amdgcn_mfma_f32_16x16x32_bf16(fah[mf], fbl, c, 0, 0, 0);
                c = __builtin_amdgcn_mfma_f32_16x16x32_bf16(fal[mf], fbh, c, 0, 0, 0);
                acc[mf][nf] = c;
            }
        }
        __syncthreads();
    }

    #pragma unroll
    for (int nf = 0; nf < 4; ++nf) {
        int ncol = n0 + wn + nf * 16 + lr;
        float bs = bias640[ncol];
        #pragma unroll
        for (int mf = 0; mf < 4; ++mf) {
            int rowb = m0 + wm + mf * 16 + rr;
            #pragma unroll
            for (int r = 0; r < 4; ++r) {
                int row = rowb + r;
                if (row < M) {
                    float v = acc[mf][nf][r] + bs;
                    if (nb < 2) valb[(size_t)row * 256 + ncol] = f2bf_rne(v);
                    else        oab[(size_t)row * 384 + (ncol - 256)] = v;
                }
            }
        }
    }
}

// ---------------------------------------------------------------------------
// Generic plane GEMM: PASSES=2 (A exact bf16, 1 plane) or 3 (A hi/lo planes).
// global_load_lds staging, linear LDS. C f32 (+Res) or bf16 (ReLU opt).
// ---------------------------------------------------------------------------
template<int PASSES, bool RELU, bool HAS_RES, bool C_BF16>
__global__ __launch_bounds__(256)
void gemm_std(const unsigned short* __restrict__ Ah,
              const unsigned short* __restrict__ Al,
              const unsigned short* __restrict__ Bh,
              const unsigned short* __restrict__ Bl,
              const float* __restrict__ bias, const float* __restrict__ Res,
              void* __restrict__ Cv, int M, int N, int K, int NB)
{
    __shared__ unsigned short sP[(PASSES + 1) * 4096];
    unsigned short* sAh = sP;
    unsigned short* sAl = sP + 4096;                     // 3-pass only
    unsigned short* sBh = sP + (PASSES - 1) * 4096;
    unsigned short* sBl = sP + PASSES * 4096;

    const int nwg = gridDim.x, bid = blockIdx.x;
    const int q8 = nwg >> 3, r8 = nwg & 7, xcd = bid & 7;
    const int work = (xcd < r8 ? xcd * (q8 + 1) : r8 * (q8 + 1) + (xcd - r8) * q8)
                     + (bid >> 3);
    const int mblk = work / NB;
    const int m0 = mblk * 128;
    const int n0 = (work - mblk * NB) * 128;

    const int tid = threadIdx.x;
    const int w = tid >> 6, l = tid & 63;
    const int wm = (w >> 1) * 64, wn = (w & 1) * 64;
    const int lr = l & 15, kb = (l >> 4) * 8, rr = (l >> 4) * 4;

    f32x4 acc[4][4];
    #pragma unroll
    for (int i = 0; i < 4; ++i)
        #pragma unroll
        for (int j = 0; j < 4; ++j) acc[i][j] = (f32x4){0.f, 0.f, 0.f, 0.f};

    for (int kt = 0; kt < K; kt += 32) {
        stage_plane(Ah, sAh, m0, K, kt, tid);
        if (PASSES == 3) stage_plane(Al, sAl, m0, K, kt, tid);
        stage_plane(Bh, sBh, n0, K, kt, tid);
        stage_plane(Bl, sBl, n0, K, kt, tid);
        __syncthreads();
        bf16x8 fah[4], fal[4];
        #pragma unroll
        for (int mf = 0; mf < 4; ++mf) {
            int off = (wm + mf * 16 + lr) * 32 + kb;
            fah[mf] = *(const bf16x8*)&sAh[off];
            if (PASSES == 3) fal[mf] = *(const bf16x8*)&sAl[off];
        }
        #pragma unroll
        for (int nf = 0; nf < 4; ++nf) {
            int boff = (wn + nf * 16 + lr) * 32 + kb;
            bf16x8 fbh = *(const bf16x8*)&sBh[boff];
            bf16x8 fbl = *(const bf16x8*)&sBl[boff];
            #pragma unroll
            for (int mf = 0; mf < 4; ++mf) {
                f32x4 c = acc[mf][nf];
                c = __builtin_amdgcn_mfma_f32_16x16x32_bf16(fah[mf], fbh, c, 0, 0, 0);
                c = __builtin_amdgcn_mfma_f32_16x16x32_bf16(fah[mf], fbl, c, 0, 0, 0);
                if (PASSES == 3)
                    c = __builtin_amdgcn_mfma_f32_16x16x32_bf16(fal[mf], fbh, c, 0, 0, 0);
                acc[mf][nf] = c;
            }
        }
        __syncthreads();
    }

    float* Cf = (float*)Cv;
    unsigned short* Cb = (unsigned short*)Cv;
    #pragma unroll
    for (int nf = 0; nf < 4; ++nf) {
        int ncol = n0 + wn + nf * 16 + lr;
        float bs = bias[ncol];
        #pragma unroll
        for (int mf = 0; mf < 4; ++mf) {
            int rowb = m0 + wm + mf * 16 + rr;
            #pragma unroll
            for (int r = 0; r < 4; ++r) {
                int row = rowb + r;
                if (row < M) {
                    float v = acc[mf][nf][r] + bs;
                    if (HAS_RES) v += Res[(size_t)row * N + ncol];
                    if (RELU) v = fmaxf(v, 0.f);
                    if (C_BF16) Cb[(size_t)row * N + ncol] = f2bf_rne(v);
                    else        Cf[(size_t)row * N + ncol] = v;
                }
            }
        }
    }
}

// ---------------------------------------------------------------------------
// Deformable sampling (as R5). Block = (q,b), XCD-swizzled q. bf16 val/out.
// ---------------------------------------------------------------------------
__global__ __launch_bounds__(256)
void sample_k(const unsigned short* __restrict__ val,
              const float* __restrict__ oab, unsigned short* __restrict__ out)
{
    const int Hs[4] = {76, 38, 19, 10};
    const int Ws[4] = {100, 50, 25, 13};
    const int ST[4] = {0, 7600, 9500, 9975};

    int bid = blockIdx.x;
    int xcd = bid & 7;
    const int qch = LQ >> 3;
    const int rem = LQ & 7;
    int q = (xcd < rem ? xcd * (qch + 1) : rem * (qch + 1) + (xcd - rem) * qch)
            + (bid >> 3);
    int b = blockIdx.y;
    int tid = threadIdx.x;

    __shared__ int2 s_iw[512];

    if (tid < 128) {
        int h = tid >> 4, pt = tid & 15, lvl = pt >> 2, p = pt & 3;
        int lq, local;
        if (q < 7600)      { lq = 0; local = q; }
        else if (q < 9500) { lq = 1; local = q - 7600; }
        else if (q < 9975) { lq = 2; local = q - 9500; }
        else               { lq = 3; local = q - 9975; }
        int Wq = Ws[lq], Hq = Hs[lq];
        int ry = local / Wq, rx = local - ry * Wq;
        float refx = (rx + 0.5f) / (float)Wq;
        float refy = (ry + 0.5f) / (float)Hq;

        size_t rowb = (size_t)(b * LQ + q) * 384;
        float logit = oab[rowb + 256 + h * 16 + pt];
        float mx = logit;
        mx = fmaxf(mx, __shfl_xor(mx, 1, 64));
        mx = fmaxf(mx, __shfl_xor(mx, 2, 64));
        mx = fmaxf(mx, __shfl_xor(mx, 4, 64));
        mx = fmaxf(mx, __shfl_xor(mx, 8, 64));
        float e = expf(logit - mx);
        float s = e;
        s += __shfl_xor(s, 1, 64);
        s += __shfl_xor(s, 2, 64);
        s += __shfl_xor(s, 4, 64);
        s += __shfl_xor(s, 8, 64);
        float aw = e / s;

        float ox = oab[rowb + h * 32 + lvl * 8 + p * 2];
        float oy = oab[rowb + h * 32 + lvl * 8 + p * 2 + 1];
        int W = Ws[lvl], H = Hs[lvl], st = ST[lvl];
        float px = refx * (float)W + ox - 0.5f;
        float py = refy * (float)H + oy - 0.5f;
        float x0f = floorf(px), y0f = floorf(py);
        float lx = px - x0f, ly = py - y0f;
        int x0 = (int)x0f, y0 = (int)y0f;
        int x1 = x0 + 1, y1 = y0 + 1;
        float ax0 = ((x0 >= 0) & (x0 < W)) ? (1.f - lx) : 0.f;
        float ax1 = ((x1 >= 0) & (x1 < W)) ? lx : 0.f;
        float ay0 = ((y0 >= 0) & (y0 < H)) ? (1.f - ly) : 0.f;
        float ay1 = ((y1 >= 0) & (y1 < H)) ? ly : 0.f;
        int cx0 = min(max(x0, 0), W - 1), cx1 = min(max(x1, 0), W - 1);
        int cy0 = min(max(y0, 0), H - 1), cy1 = min(max(y1, 0), H - 1);
        int i00 = st + cy0 * W + cx0, i01 = st + cy0 * W + cx1;
        int i10 = st + cy1 * W + cx0, i11 = st + cy1 * W + cx1;
        int base4 = tid * 4;
        s_iw[base4 + 0] = make_int2(i00, __float_as_int(aw * ay0 * ax0));
        s_iw[base4 + 1] = make_int2(i01, __float_as_int(aw * ay0 * ax1));
        s_iw[base4 + 2] = make_int2(i10, __float_as_int(aw * ay1 * ax0));
        s_iw[base4 + 3] = make_int2(i11, __float_as_int(aw * ay1 * ax1));
    }
    __syncthreads();

    int lane   = tid & 63;
    int wv     = tid >> 6;
    int h      = wv * 2 + (lane >> 5);
    int half   = lane & 31;
    int corner = half >> 3;
    int c4     = half & 7;
    const unsigned short* vb = val + (size_t)(b * LQ) * 256 + h * 32 + c4 * 4;
    int sbase = h * 64 + corner;

    float4 acc = make_float4(0.f, 0.f, 0.f, 0.f);
    #pragma unroll
    for (int pt = 0; pt < 16; ++pt) {
        int2 iw = s_iw[sbase + pt * 4];
        float wgt = __int_as_float(iw.y);
        ushort4 v = *(const ushort4*)&vb[(size_t)iw.x * 256];
        acc.x += wgt * bf2f(v.x); acc.y += wgt * bf2f(v.y);
        acc.z += wgt * bf2f(v.z); acc.w += wgt * bf2f(v.w);
    }
    acc.x += __shfl_xor(acc.x, 8, 64);  acc.y += __shfl_xor(acc.y, 8, 64);
    acc.z += __shfl_xor(acc.z, 8, 64);  acc.w += __shfl_xor(acc.w, 8, 64);
    acc.x += __shfl_xor(acc.x, 16, 64); acc.y += __shfl_xor(acc.y, 16, 64);
    acc.z += __shfl_xor(acc.z, 16, 64); acc.w += __shfl_xor(acc.w, 16, 64);

    if (corner == 0) {
        ushort4 o;
        o.x = f2bf_rne(acc.x); o.y = f2bf_rne(acc.y);
        o.z = f2bf_rne(acc.z); o.w = f2bf_rne(acc.w);
        *(ushort4*)&out[(size_t)(b * LQ + q) * 256 + h * 32 + c4 * 4] = o;
    }
}

// ---------------------------------------------------------------------------
// LayerNorm D=256 + plane emission. 4 rows/block, one wave/row, float4/lane.
// EMIT_PLANES: hi/lo planes of LN output; EMIT_Q: hi/lo planes of out+pos.
// ---------------------------------------------------------------------------
template<bool EMIT_Q, bool EMIT_PLANES>
__global__ __launch_bounds__(256)
void ln_plane_k(const float* __restrict__ x, const float* __restrict__ g,
                const float* __restrict__ bt, const float* __restrict__ pos,
                float* __restrict__ dst, unsigned short* __restrict__ sh,
                unsigned short* __restrict__ sl, unsigned short* __restrict__ qh,
                unsigned short* __restrict__ ql, int nrows)
{
    int row = blockIdx.x * 4 + (threadIdx.x >> 6);
    int lane = threadIdx.x & 63;
    if (row >= nrows) return;

    float4 v = *(const float4*)&x[(size_t)row * 256 + lane * 4];
    float s = v.x + v.y + v.z + v.w;
    #pragma unroll
    for (int o = 32; o > 0; o >>= 1) s += __shfl_down(s, o, 64);
    s = __shfl(s, 0, 64);
    float m = s * (1.0f / 256.0f);
    float cx = v.x - m, cy = v.y - m, cz = v.z - m, cw = v.w - m;
    float s2 = cx * cx + cy * cy + cz * cz + cw * cw;
    #pragma unroll
    for (int o = 32; o > 0; o >>= 1) s2 += __shfl_down(s2, o, 64);
    s2 = __shfl(s2, 0, 64);
    float rstd = rsqrtf(s2 * (1.0f / 256.0f) + 1e-5f);

    float4 gv = *(const float4*)&g[lane * 4];
    float4 bv = *(const float4*)&bt[lane * 4];
    float4 r;
    r.x = cx * rstd * gv.x + bv.x;
    r.y = cy * rstd * gv.y + bv.y;
    r.z = cz * rstd * gv.z + bv.z;
    r.w = cw * rstd * gv.w + bv.w;
    size_t o4 = (size_t)row * 256 + lane * 4;
    *(float4*)&dst[o4] = r;

    if (EMIT_PLANES) {
        ushort4 hh, ll;
        split2(r.x, hh.x, ll.x); split2(r.y, hh.y, ll.y);
        split2(r.z, hh.z, ll.z); split2(r.w, hh.w, ll.w);
        *(ushort4*)&sh[o4] = hh;
        *(ushort4*)&sl[o4] = ll;
    }
    if (EMIT_Q) {
        float4 pv = *(const float4*)&pos[o4];
        ushort4 hh, ll;
        split2(r.x + pv.x, hh.x, ll.x); split2(r.y + pv.y, hh.y, ll.y);
        split2(r.z + pv.z, hh.z, ll.z); split2(r.w + pv.w, hh.w, ll.w);
        *(ushort4*)&qh[o4] = hh;
        *(ushort4*)&ql[o4] = ll;
    }
}

// ---------------------------------------------------------------------------
extern "C" void kernel_launch(void* const* d_in, const int* in_sizes, int n_in,
                              void* d_out, int out_size, void* d_ws, size_t ws_size,
                              hipStream_t stream)
{
    const float* src_in[4] = {(const float*)d_in[0], (const float*)d_in[2],
                              (const float*)d_in[4], (const float*)d_in[6]};
    const float* pos_in[4] = {(const float*)d_in[1], (const float*)d_in[3],
                              (const float*)d_in[5], (const float*)d_in[7]};
    const float* lvl    = (const float*)d_in[8];
    const float* w_off  = (const float*)d_in[9];
    const float* b_off  = (const float*)d_in[10];
    const float* w_attn = (const float*)d_in[11];
    const float* b_attn = (const float*)d_in[12];
    const float* w_val  = (const float*)d_in[13];
    const float* b_val  = (const float*)d_in[14];
    const float* w_out  = (const float*)d_in[15];
    const float* b_out  = (const float*)d_in[16];
    const float* ln1_g  = (const float*)d_in[17];
    const float* ln1_b  = (const float*)d_in[18];
    const float* w_ffn1 = (const float*)d_in[19];
    const float* b_ffn1 = (const float*)d_in[20];
    const float* w_ffn2 = (const float*)d_in[21];
    const float* b_ffn2 = (const float*)d_in[22];
    const float* ln2_g  = (const float*)d_in[23];
    const float* ln2_b  = (const float*)d_in[24];

    // ---- workspace layout ----
    char* wsb = (char*)d_ws;
    float* src  = (float*)wsb;                                   // NTOK*256 f32
    float* pos  = src + (size_t)NTOK * 256;                      // NTOK*256 f32
    float* preln = pos + (size_t)NTOK * 256;                     // NTOK*256 f32
    unsigned short* sh = (unsigned short*)(preln + (size_t)NTOK * 256); // planes
    unsigned short* sl = sh + (size_t)NTOK * 256;
    unsigned short* qh = sl + (size_t)NTOK * 256;
    unsigned short* ql = qh + (size_t)NTOK * 256;
    char* uni = (char*)(ql + (size_t)NTOK * 256);
    unsigned short* valb = (unsigned short*)uni;                        // NTOK*256 u16
    float* oab = (float*)(uni + (size_t)NTOK * 512);                    // NTOK*384 f32
    unsigned short* samp = (unsigned short*)(uni + (size_t)NTOK * 2048);// NTOK*256 u16
    unsigned short* ffnb = (unsigned short*)uni;                        // NTOK*1024 u16
    float* boa640 = (float*)(uni + (size_t)NTOK * 2560);                // 6*640
    unsigned short* Wh = (unsigned short*)(boa640 + 6 * 640);
    const long WL = 753664;                         // per-layer bf16 elems
    unsigned short* Wl = Wh + (size_t)NLAYERS * WL;
    const long O_VAL = 0, O_OFF = 65536, O_ATT = 131072, O_OUT = 163840,
               O_F1 = 229376, O_F2 = 491520;

    // ---- weight prep ----
    wsplit_k<<<dim3(8, 8, 6),  256, 0, stream>>>(w_val,  Wh + O_VAL, Wl + O_VAL, 256, 256,  65536, WL);
    wsplit_k<<<dim3(8, 8, 6),  256, 0, stream>>>(w_off,  Wh + O_OFF, Wl + O_OFF, 256, 256,  65536, WL);
    wsplit_k<<<dim3(4, 8, 6),  256, 0, stream>>>(w_attn, Wh + O_ATT, Wl + O_ATT, 256, 128,  32768, WL);
    wsplit_k<<<dim3(8, 8, 6),  256, 0, stream>>>(w_out,  Wh + O_OUT, Wl + O_OUT, 256, 256,  65536, WL);
    wsplit_k<<<dim3(32, 8, 6), 256, 0, stream>>>(w_ffn1, Wh + O_F1,  Wl + O_F1,  256, 1024, 262144, WL);
    wsplit_k<<<dim3(8, 32, 6), 256, 0, stream>>>(w_ffn2, Wh + O_F2,  Wl + O_F2,  1024, 256, 262144, WL);
    boa_k<<<dim3(6), dim3(640), 0, stream>>>(b_val, b_off, b_attn, boa640);

    const int HWs[4] = {7600, 1900, 475, 130};
    const int STt[4] = {0, 7600, 9500, 9975};
    for (int l = 0; l < 4; ++l) {
        dim3 g((HWs[l] + 63) / 64, 4, BATCH);
        flatten_k<<<g, 256, 0, stream>>>(src_in[l], pos_in[l], lvl + l * 256,
                                         src, pos, sh, sl, qh, ql, HWs[l], STt[l]);
    }

    const int MB = (NTOK + 127) / 128;   // 158
    const int LNB = (NTOK + 3) / 4;      // 5053
    dim3 blk(256);

    for (int i = 0; i < NLAYERS; ++i) {
        const unsigned short* whL = Wh + (size_t)i * WL;
        const unsigned short* wlL = Wl + (size_t)i * WL;
        const float* bou = b_out  + (size_t)i * 256;
        const float* l1g = ln1_g  + (size_t)i * 256;
        const float* l1b = ln1_b  + (size_t)i * 256;
        const float* bf1 = b_ffn1 + (size_t)i * 1024;
        const float* bf2 = b_ffn2 + (size_t)i * 256;
        const float* l2g = ln2_g  + (size_t)i * 256;
        const float* l2b = ln2_b  + (size_t)i * 256;

        // fused [val | off | attn]: N=640, A planes per n-block
        gemm_top<<<dim3(MB * 5), blk, 0, stream>>>(
            sh, sl, qh, ql, whL, wlL, boa640 + (size_t)i * 640, valb, oab, NTOK);
        // deformable sampling -> samp (bf16)
        sample_k<<<dim3(LQ, BATCH), blk, 0, stream>>>(valb, oab, samp);
        // attn_out = samp @ w_out + b_out + src -> preln
        gemm_std<2, false, true, false><<<dim3(MB * 2), blk, 0, stream>>>(
            samp, nullptr, whL + O_OUT, wlL + O_OUT, bou, src, preln,
            NTOK, 256, 256, 2);
        // LN1 -> src + src planes
        ln_plane_k<false, true><<<dim3(LNB), blk, 0, stream>>>(
            preln, l1g, l1b, nullptr, src, sh, sl, nullptr, nullptr, NTOK);
        // ffn1 = relu(src @ w_ffn1 + b) -> ffnb (bf16), A = src planes
        gemm_std<3, true, false, true><<<dim3(MB * 8), blk, 0, stream>>>(
            sh, sl, whL + O_F1, wlL + O_F1, bf1, nullptr, ffnb,
            NTOK, 1024, 256, 8);
        // ffn2 = ffnb @ w_ffn2 + b + src -> preln
        gemm_std<2, false, true, false><<<dim3(MB * 2), blk, 0, stream>>>(
            ffnb, nullptr, whL + O_F2, wlL + O_F2, bf2, src, preln,
            NTOK, 256, 1024, 2);
        // LN2 -> src + planes + q planes (or d_out on last layer)
        if (i == NLAYERS - 1)
            ln_plane_k<false, false><<<dim3(LNB), blk, 0, stream>>>(
                preln, l2g, l2b, nullptr, (float*)d_out,
                nullptr, nullptr, nullptr, nullptr, NTOK);
        else
            ln_plane_k<true, true><<<dim3(LNB), blk, 0, stream>>>(
                preln, l2g, l2b, pos, src, sh, sl, qh, ql, NTOK);
    }
}

// Round 7
// 1718.548 us; speedup vs baseline: 1.0426x; 1.0426x over previous
//
#include <hip/hip_runtime.h>
#include <math.h>

#define LQ 10105
#define BATCH 2
#define NLAYERS 6
#define NTOK (BATCH * LQ)   // 20210

typedef __attribute__((ext_vector_type(8))) short bf16x8;   // 8 bf16 (4 VGPRs)
typedef __attribute__((ext_vector_type(4))) float f32x4;

__device__ inline unsigned short f2bf_rne(float f) {
    unsigned u = __float_as_uint(f);
    unsigned r = u + 0x7fffu + ((u >> 16) & 1u);
    return (unsigned short)(r >> 16);
}
__device__ inline float bf2f(unsigned short h) {
    return __uint_as_float((unsigned)h << 16);
}
// truncation hi/lo split
__device__ inline void split2(float v, unsigned short& h, unsigned short& l) {
    h = (unsigned short)(__float_as_uint(v) >> 16);
    float r = v - bf2f(h);
    l = (unsigned short)(__float_as_uint(r) >> 16);
}

// async global->LDS staging of one 128x32 bf16 plane, k-slot XOR-swizzled at
// the GLOBAL source (LDS dest stays linear; read side applies same XOR).
__device__ inline void stage_plane(const unsigned short* __restrict__ gp,
                                   unsigned short* lp, int row0, int K, int kt,
                                   int tid)
{
    int rloc = tid >> 2;
    int slot = (tid & 3) ^ ((tid >> 3) & 3);   // involution within 8-row stripe
    int kk   = kt + slot * 8;
    __builtin_amdgcn_global_load_lds(
        (const __attribute__((address_space(1))) void*)(gp + (size_t)(row0 + rloc) * K + kk),
        (__attribute__((address_space(3))) void*)(lp + tid * 8), 16, 0, 0);
    __builtin_amdgcn_global_load_lds(
        (const __attribute__((address_space(1))) void*)(gp + (size_t)(row0 + rloc + 64) * K + kk),
        (__attribute__((address_space(3))) void*)(lp + 2048 + tid * 8), 16, 0, 0);
}

// ---------------------------------------------------------------------------
// Flatten: (B,D,H,W) -> (B,HW,D) with LDS transpose; emits src f32, pos f32,
// src hi/lo planes, q=src+pos hi/lo planes.
// ---------------------------------------------------------------------------
__global__ __launch_bounds__(256)
void flatten_k(const float* __restrict__ src, const float* __restrict__ pos,
               const float* __restrict__ lvl, float* __restrict__ srcf,
               float* __restrict__ posf, unsigned short* __restrict__ sh,
               unsigned short* __restrict__ sl, unsigned short* __restrict__ qh,
               unsigned short* __restrict__ ql, int HW, int start)
{
    __shared__ float ts[64][65], tp[64][65];
    int hw0 = blockIdx.x * 64;
    int d0  = blockIdx.y * 64;
    int b   = blockIdx.z;
    int tid = threadIdx.x;
    int c = tid & 63, rg = tid >> 6;

    #pragma unroll 4
    for (int i = 0; i < 16; ++i) {
        int dl = rg * 16 + i;
        int hw = hw0 + c;
        float s = 0.f, p = 0.f;
        if (hw < HW) {
            s = src[(size_t)(b * 256 + d0 + dl) * HW + hw];
            p = pos[(size_t)(b * 256 + d0 + dl) * HW + hw];
        }
        ts[dl][c] = s;
        tp[dl][c] = p;
    }
    __syncthreads();
    float lv = lvl[d0 + c];
    #pragma unroll 4
    for (int i = 0; i < 16; ++i) {
        int hwl = rg * 16 + i;
        int hw = hw0 + hwl;
        if (hw >= HW) continue;
        float s = ts[c][hwl] + lv;
        float p = tp[c][hwl];
        size_t o = (size_t)(b * LQ + start + hw) * 256 + d0 + c;
        srcf[o] = s;
        posf[o] = p;
        unsigned short h, l;
        split2(s, h, l); sh[o] = h; sl[o] = l;
        float q = s + p;
        split2(q, h, l); qh[o] = h; ql[o] = l;
    }
}

// ---------------------------------------------------------------------------
// Weight transpose + bf16 hi/lo split: W[L][K][N] fp32 -> Th/Tl[L][N][K] bf16
// ---------------------------------------------------------------------------
__global__ __launch_bounds__(256)
void wsplit_k(const float* __restrict__ W, unsigned short* __restrict__ Th,
              unsigned short* __restrict__ Tl, int K, int N,
              long srcStride, long dstStride)
{
    __shared__ float t[32][33];
    int layer = blockIdx.z;
    int n0 = blockIdx.x * 32, k0 = blockIdx.y * 32;
    int tx = threadIdx.x & 31, ty = threadIdx.x >> 5;
    const float* Wsrc = W + (size_t)layer * srcStride;
    #pragma unroll
    for (int i = 0; i < 4; ++i)
        t[ty + i * 8][tx] = Wsrc[(size_t)(k0 + ty + i * 8) * N + n0 + tx];
    __syncthreads();
    unsigned short* th = Th + (size_t)layer * dstStride;
    unsigned short* tl = Tl + (size_t)layer * dstStride;
    #pragma unroll
    for (int i = 0; i < 4; ++i) {
        int n = n0 + ty + i * 8;
        float v = t[tx][ty + i * 8];
        unsigned short h = f2bf_rne(v);
        th[(size_t)n * K + k0 + tx] = h;
        tl[(size_t)n * K + k0 + tx] = f2bf_rne(v - bf2f(h));
    }
}

// combined bias [b_val | b_off | b_attn] -> 640 per layer
__global__ void boa_k(const float* __restrict__ b_val,
                      const float* __restrict__ b_off,
                      const float* __restrict__ b_attn, float* __restrict__ bo)
{
    int l = blockIdx.x, t = threadIdx.x;   // 640 threads
    float v;
    if (t < 256)      v = b_val[l * 256 + t];
    else if (t < 512) v = b_off[l * 256 + (t - 256)];
    else              v = b_attn[l * 128 + (t - 512)];
    bo[l * 640 + t] = v;
}

// ---------------------------------------------------------------------------
// Fused top GEMM: C[:,0:256]=src@w_val -> valb bf16; C[:,256:640]=(q)@[w_off|
// w_attn] -> oab f32. 3-pass split MFMA, double-buffered LDS, swizzled reads.
// ---------------------------------------------------------------------------
__global__ __launch_bounds__(256)
void gemm_top(const unsigned short* __restrict__ Ash,
              const unsigned short* __restrict__ Asl,
              const unsigned short* __restrict__ Aqh,
              const unsigned short* __restrict__ Aql,
              const unsigned short* __restrict__ Bh,
              const unsigned short* __restrict__ Bl,
              const float* __restrict__ bias640,
              unsigned short* __restrict__ valb, float* __restrict__ oab, int M)
{
    constexpr int K = 256, NB = 5;
    __shared__ unsigned short sP[2 * 4 * 4096];  // 2 buf x (Ah|Al|Bh|Bl)

    const int nwg = gridDim.x, bid = blockIdx.x;
    const int q8 = nwg >> 3, r8 = nwg & 7, xcd = bid & 7;
    const int work = (xcd < r8 ? xcd * (q8 + 1) : r8 * (q8 + 1) + (xcd - r8) * q8)
                     + (bid >> 3);
    const int mblk = work / NB;
    const int nb = work - mblk * NB;
    const int m0 = mblk * 128, n0 = nb * 128;

    const unsigned short* Ah = (nb < 2) ? Ash : Aqh;
    const unsigned short* Al = (nb < 2) ? Asl : Aql;

    const int tid = threadIdx.x;
    const int w = tid >> 6, l = tid & 63;
    const int wm = (w >> 1) * 64, wn = (w & 1) * 64;
    const int lr = l & 15, rr = (l >> 4) * 4;
    const int so = (((l >> 4) ^ ((lr >> 1) & 3)) * 8);   // swizzled k-slot

    f32x4 acc[4][4];
    #pragma unroll
    for (int i = 0; i < 4; ++i)
        #pragma unroll
        for (int j = 0; j < 4; ++j) acc[i][j] = (f32x4){0.f, 0.f, 0.f, 0.f};

    auto STAGE = [&](int b, int kt) {
        unsigned short* base = sP + b * 16384;
        stage_plane(Ah, base,         m0, K, kt, tid);
        stage_plane(Al, base + 4096,  m0, K, kt, tid);
        stage_plane(Bh, base + 8192,  n0, K, kt, tid);
        stage_plane(Bl, base + 12288, n0, K, kt, tid);
    };
    auto COMPUTE = [&](int b) {
        unsigned short* base = sP + b * 16384;
        bf16x8 fah[4], fal[4];
        #pragma unroll
        for (int mf = 0; mf < 4; ++mf) {
            int off = (wm + mf * 16 + lr) * 32 + so;
            fah[mf] = *(const bf16x8*)&base[off];
            fal[mf] = *(const bf16x8*)&base[4096 + off];
        }
        #pragma unroll
        for (int nf = 0; nf < 4; ++nf) {
            int boff = (wn + nf * 16 + lr) * 32 + so;
            bf16x8 fbh = *(const bf16x8*)&base[8192 + boff];
            bf16x8 fbl = *(const bf16x8*)&base[12288 + boff];
            #pragma unroll
            for (int mf = 0; mf < 4; ++mf) {
                f32x4 c = acc[mf][nf];
                c = __builtin_amdgcn_mfma_f32_16x16x32_bf16(fah[mf], fbh, c, 0, 0, 0);
                c = __builtin_amdgcn_mfma_f32_16x16x32_bf16(fah[mf], fbl, c, 0, 0, 0);
                c = __builtin_amdgcn_mfma_f32_16x16x32_bf16(fal[mf], fbh, c, 0, 0, 0);
                acc[mf][nf] = c;
            }
        }
    };

    STAGE(0, 0);
    __syncthreads();
    for (int kt = 0; kt < K; kt += 64) {
        STAGE(1, kt + 32);
        COMPUTE(0);
        __syncthreads();
        if (kt + 64 < K) STAGE(0, kt + 64);
        COMPUTE(1);
        __syncthreads();
    }

    #pragma unroll
    for (int nf = 0; nf < 4; ++nf) {
        int ncol = n0 + wn + nf * 16 + lr;
        float bs = bias640[ncol];
        #pragma unroll
        for (int mf = 0; mf < 4; ++mf) {
            int rowb = m0 + wm + mf * 16 + rr;
            #pragma unroll
            for (int r = 0; r < 4; ++r) {
                int row = rowb + r;
                if (row < M) {
                    float v = acc[mf][nf][r] + bs;
                    if (nb < 2) valb[(size_t)row * 256 + ncol] = f2bf_rne(v);
                    else        oab[(size_t)row * 384 + (ncol - 256)] = v;
                }
            }
        }
    }
}

// ---------------------------------------------------------------------------
// Generic plane GEMM: PASSES=2 (A exact bf16) or 3 (A hi/lo planes).
// Double-buffered LDS, global_load_lds staging, swizzled fragment reads.
// ---------------------------------------------------------------------------
template<int PASSES, bool RELU, bool HAS_RES, bool C_BF16>
__global__ __launch_bounds__(256)
void gemm_std(const unsigned short* __restrict__ Ah,
              const unsigned short* __restrict__ Al,
              const unsigned short* __restrict__ Bh,
              const unsigned short* __restrict__ Bl,
              const float* __restrict__ bias, const float* __restrict__ Res,
              void* __restrict__ Cv, int M, int N, int K, int NB)
{
    constexpr int NPL = PASSES + 1;
    __shared__ unsigned short sP[2 * NPL * 4096];

    const int nwg = gridDim.x, bid = blockIdx.x;
    const int q8 = nwg >> 3, r8 = nwg & 7, xcd = bid & 7;
    const int work = (xcd < r8 ? xcd * (q8 + 1) : r8 * (q8 + 1) + (xcd - r8) * q8)
                     + (bid >> 3);
    const int mblk = work / NB;
    const int m0 = mblk * 128;
    const int n0 = (work - mblk * NB) * 128;

    const int tid = threadIdx.x;
    const int w = tid >> 6, l = tid & 63;
    const int wm = (w >> 1) * 64, wn = (w & 1) * 64;
    const int lr = l & 15, rr = (l >> 4) * 4;
    const int so = (((l >> 4) ^ ((lr >> 1) & 3)) * 8);

    f32x4 acc[4][4];
    #pragma unroll
    for (int i = 0; i < 4; ++i)
        #pragma unroll
        for (int j = 0; j < 4; ++j) acc[i][j] = (f32x4){0.f, 0.f, 0.f, 0.f};

    auto STAGE = [&](int b, int kt) {
        unsigned short* base = sP + b * (NPL * 4096);
        stage_plane(Ah, base, m0, K, kt, tid);
        if (PASSES == 3) stage_plane(Al, base + 4096, m0, K, kt, tid);
        stage_plane(Bh, base + (PASSES - 1) * 4096, n0, K, kt, tid);
        stage_plane(Bl, base + PASSES * 4096, n0, K, kt, tid);
    };
    auto COMPUTE = [&](int b) {
        unsigned short* base = sP + b * (NPL * 4096);
        bf16x8 fah[4], fal[4];
        #pragma unroll
        for (int mf = 0; mf < 4; ++mf) {
            int off = (wm + mf * 16 + lr) * 32 + so;
            fah[mf] = *(const bf16x8*)&base[off];
            if (PASSES == 3) fal[mf] = *(const bf16x8*)&base[4096 + off];
        }
        #pragma unroll
        for (int nf = 0; nf < 4; ++nf) {
            int boff = (wn + nf * 16 + lr) * 32 + so;
            bf16x8 fbh = *(const bf16x8*)&base[(PASSES - 1) * 4096 + boff];
            bf16x8 fbl = *(const bf16x8*)&base[PASSES * 4096 + boff];
            #pragma unroll
            for (int mf = 0; mf < 4; ++mf) {
                f32x4 c = acc[mf][nf];
                c = __builtin_amdgcn_mfma_f32_16x16x32_bf16(fah[mf], fbh, c, 0, 0, 0);
                c = __builtin_amdgcn_mfma_f32_16x16x32_bf16(fah[mf], fbl, c, 0, 0, 0);
                if (PASSES == 3)
                    c = __builtin_amdgcn_mfma_f32_16x16x32_bf16(fal[mf], fbh, c, 0, 0, 0);
                acc[mf][nf] = c;
            }
        }
    };

    STAGE(0, 0);
    __syncthreads();
    for (int kt = 0; kt < K; kt += 64) {
        STAGE(1, kt + 32);
        COMPUTE(0);
        __syncthreads();
        if (kt + 64 < K) STAGE(0, kt + 64);
        COMPUTE(1);
        __syncthreads();
    }

    float* Cf = (float*)Cv;
    unsigned short* Cb = (unsigned short*)Cv;
    #pragma unroll
    for (int nf = 0; nf < 4; ++nf) {
        int ncol = n0 + wn + nf * 16 + lr;
        float bs = bias[ncol];
        #pragma unroll
        for (int mf = 0; mf < 4; ++mf) {
            int rowb = m0 + wm + mf * 16 + rr;
            #pragma unroll
            for (int r = 0; r < 4; ++r) {
                int row = rowb + r;
                if (row < M) {
                    float v = acc[mf][nf][r] + bs;
                    if (HAS_RES) v += Res[(size_t)row * N + ncol];
                    if (RELU) v = fmaxf(v, 0.f);
                    if (C_BF16) Cb[(size_t)row * N + ncol] = f2bf_rne(v);
                    else        Cf[(size_t)row * N + ncol] = v;
                }
            }
        }
    }
}

// ---------------------------------------------------------------------------
// Deformable sampling. Block = (q,b), XCD-swizzled q. bf16 val/out.
// ---------------------------------------------------------------------------
__global__ __launch_bounds__(256)
void sample_k(const unsigned short* __restrict__ val,
              const float* __restrict__ oab, unsigned short* __restrict__ out)
{
    const int Hs[4] = {76, 38, 19, 10};
    const int Ws[4] = {100, 50, 25, 13};
    const int ST[4] = {0, 7600, 9500, 9975};

    int bid = blockIdx.x;
    int xcd = bid & 7;
    const int qch = LQ >> 3;
    const int rem = LQ & 7;
    int q = (xcd < rem ? xcd * (qch + 1) : rem * (qch + 1) + (xcd - rem) * qch)
            + (bid >> 3);
    int b = blockIdx.y;
    int tid = threadIdx.x;

    __shared__ int2 s_iw[512];

    if (tid < 128) {
        int h = tid >> 4, pt = tid & 15, lvl = pt >> 2, p = pt & 3;
        int lq, local;
        if (q < 7600)      { lq = 0; local = q; }
        else if (q < 9500) { lq = 1; local = q - 7600; }
        else if (q < 9975) { lq = 2; local = q - 9500; }
        else               { lq = 3; local = q - 9975; }
        int Wq = Ws[lq], Hq = Hs[lq];
        int ry = local / Wq, rx = local - ry * Wq;
        float refx = (rx + 0.5f) / (float)Wq;
        float refy = (ry + 0.5f) / (float)Hq;

        size_t rowb = (size_t)(b * LQ + q) * 384;
        float logit = oab[rowb + 256 + h * 16 + pt];
        float mx = logit;
        mx = fmaxf(mx, __shfl_xor(mx, 1, 64));
        mx = fmaxf(mx, __shfl_xor(mx, 2, 64));
        mx = fmaxf(mx, __shfl_xor(mx, 4, 64));
        mx = fmaxf(mx, __shfl_xor(mx, 8, 64));
        float e = expf(logit - mx);
        float s = e;
        s += __shfl_xor(s, 1, 64);
        s += __shfl_xor(s, 2, 64);
        s += __shfl_xor(s, 4, 64);
        s += __shfl_xor(s, 8, 64);
        float aw = e / s;

        float ox = oab[rowb + h * 32 + lvl * 8 + p * 2];
        float oy = oab[rowb + h * 32 + lvl * 8 + p * 2 + 1];
        int W = Ws[lvl], H = Hs[lvl], st = ST[lvl];
        float px = refx * (float)W + ox - 0.5f;
        float py = refy * (float)H + oy - 0.5f;
        float x0f = floorf(px), y0f = floorf(py);
        float lx = px - x0f, ly = py - y0f;
        int x0 = (int)x0f, y0 = (int)y0f;
        int x1 = x0 + 1, y1 = y0 + 1;
        float ax0 = ((x0 >= 0) & (x0 < W)) ? (1.f - lx) : 0.f;
        float ax1 = ((x1 >= 0) & (x1 < W)) ? lx : 0.f;
        float ay0 = ((y0 >= 0) & (y0 < H)) ? (1.f - ly) : 0.f;
        float ay1 = ((y1 >= 0) & (y1 < H)) ? ly : 0.f;
        int cx0 = min(max(x0, 0), W - 1), cx1 = min(max(x1, 0), W - 1);
        int cy0 = min(max(y0, 0), H - 1), cy1 = min(max(y1, 0), H - 1);
        int i00 = st + cy0 * W + cx0, i01 = st + cy0 * W + cx1;
        int i10 = st + cy1 * W + cx0, i11 = st + cy1 * W + cx1;
        int base4 = tid * 4;
        s_iw[base4 + 0] = make_int2(i00, __float_as_int(aw * ay0 * ax0));
        s_iw[base4 + 1] = make_int2(i01, __float_as_int(aw * ay0 * ax1));
        s_iw[base4 + 2] = make_int2(i10, __float_as_int(aw * ay1 * ax0));
        s_iw[base4 + 3] = make_int2(i11, __float_as_int(aw * ay1 * ax1));
    }
    __syncthreads();

    int lane   = tid & 63;
    int wv     = tid >> 6;
    int h      = wv * 2 + (lane >> 5);
    int half   = lane & 31;
    int corner = half >> 3;
    int c4     = half & 7;
    const unsigned short* vb = val + (size_t)(b * LQ) * 256 + h * 32 + c4 * 4;
    int sbase = h * 64 + corner;

    float4 acc = make_float4(0.f, 0.f, 0.f, 0.f);
    #pragma unroll
    for (int pt = 0; pt < 16; ++pt) {
        int2 iw = s_iw[sbase + pt * 4];
        float wgt = __int_as_float(iw.y);
        ushort4 v = *(const ushort4*)&vb[(size_t)iw.x * 256];
        acc.x += wgt * bf2f(v.x); acc.y += wgt * bf2f(v.y);
        acc.z += wgt * bf2f(v.z); acc.w += wgt * bf2f(v.w);
    }
    acc.x += __shfl_xor(acc.x, 8, 64);  acc.y += __shfl_xor(acc.y, 8, 64);
    acc.z += __shfl_xor(acc.z, 8, 64);  acc.w += __shfl_xor(acc.w, 8, 64);
    acc.x += __shfl_xor(acc.x, 16, 64); acc.y += __shfl_xor(acc.y, 16, 64);
    acc.z += __shfl_xor(acc.z, 16, 64); acc.w += __shfl_xor(acc.w, 16, 64);

    if (corner == 0) {
        ushort4 o;
        o.x = f2bf_rne(acc.x); o.y = f2bf_rne(acc.y);
        o.z = f2bf_rne(acc.z); o.w = f2bf_rne(acc.w);
        *(ushort4*)&out[(size_t)(b * LQ + q) * 256 + h * 32 + c4 * 4] = o;
    }
}

// ---------------------------------------------------------------------------
// LayerNorm D=256 + plane emission. 4 rows/block, one wave/row, float4/lane.
// ---------------------------------------------------------------------------
template<bool EMIT_Q, bool EMIT_PLANES>
__global__ __launch_bounds__(256)
void ln_plane_k(const float* __restrict__ x, const float* __restrict__ g,
                const float* __restrict__ bt, const float* __restrict__ pos,
                float* __restrict__ dst, unsigned short* __restrict__ sh,
                unsigned short* __restrict__ sl, unsigned short* __restrict__ qh,
                unsigned short* __restrict__ ql, int nrows)
{
    int row = blockIdx.x * 4 + (threadIdx.x >> 6);
    int lane = threadIdx.x & 63;
    if (row >= nrows) return;

    float4 v = *(const float4*)&x[(size_t)row * 256 + lane * 4];
    float s = v.x + v.y + v.z + v.w;
    #pragma unroll
    for (int o = 32; o > 0; o >>= 1) s += __shfl_down(s, o, 64);
    s = __shfl(s, 0, 64);
    float m = s * (1.0f / 256.0f);
    float cx = v.x - m, cy = v.y - m, cz = v.z - m, cw = v.w - m;
    float s2 = cx * cx + cy * cy + cz * cz + cw * cw;
    #pragma unroll
    for (int o = 32; o > 0; o >>= 1) s2 += __shfl_down(s2, o, 64);
    s2 = __shfl(s2, 0, 64);
    float rstd = rsqrtf(s2 * (1.0f / 256.0f) + 1e-5f);

    float4 gv = *(const float4*)&g[lane * 4];
    float4 bv = *(const float4*)&bt[lane * 4];
    float4 r;
    r.x = cx * rstd * gv.x + bv.x;
    r.y = cy * rstd * gv.y + bv.y;
    r.z = cz * rstd * gv.z + bv.z;
    r.w = cw * rstd * gv.w + bv.w;
    size_t o4 = (size_t)row * 256 + lane * 4;
    *(float4*)&dst[o4] = r;

    if (EMIT_PLANES) {
        ushort4 hh, ll;
        split2(r.x, hh.x, ll.x); split2(r.y, hh.y, ll.y);
        split2(r.z, hh.z, ll.z); split2(r.w, hh.w, ll.w);
        *(ushort4*)&sh[o4] = hh;
        *(ushort4*)&sl[o4] = ll;
    }
    if (EMIT_Q) {
        float4 pv = *(const float4*)&pos[o4];
        ushort4 hh, ll;
        split2(r.x + pv.x, hh.x, ll.x); split2(r.y + pv.y, hh.y, ll.y);
        split2(r.z + pv.z, hh.z, ll.z); split2(r.w + pv.w, hh.w, ll.w);
        *(ushort4*)&qh[o4] = hh;
        *(ushort4*)&ql[o4] = ll;
    }
}

// ---------------------------------------------------------------------------
extern "C" void kernel_launch(void* const* d_in, const int* in_sizes, int n_in,
                              void* d_out, int out_size, void* d_ws, size_t ws_size,
                              hipStream_t stream)
{
    const float* src_in[4] = {(const float*)d_in[0], (const float*)d_in[2],
                              (const float*)d_in[4], (const float*)d_in[6]};
    const float* pos_in[4] = {(const float*)d_in[1], (const float*)d_in[3],
                              (const float*)d_in[5], (const float*)d_in[7]};
    const float* lvl    = (const float*)d_in[8];
    const float* w_off  = (const float*)d_in[9];
    const float* b_off  = (const float*)d_in[10];
    const float* w_attn = (const float*)d_in[11];
    const float* b_attn = (const float*)d_in[12];
    const float* w_val  = (const float*)d_in[13];
    const float* b_val  = (const float*)d_in[14];
    const float* w_out  = (const float*)d_in[15];
    const float* b_out  = (const float*)d_in[16];
    const float* ln1_g  = (const float*)d_in[17];
    const float* ln1_b  = (const float*)d_in[18];
    const float* w_ffn1 = (const float*)d_in[19];
    const float* b_ffn1 = (const float*)d_in[20];
    const float* w_ffn2 = (const float*)d_in[21];
    const float* b_ffn2 = (const float*)d_in[22];
    const float* ln2_g  = (const float*)d_in[23];
    const float* ln2_b  = (const float*)d_in[24];

    // ---- workspace layout ----
    char* wsb = (char*)d_ws;
    float* src  = (float*)wsb;                                   // NTOK*256 f32
    float* pos  = src + (size_t)NTOK * 256;                      // NTOK*256 f32
    float* preln = pos + (size_t)NTOK * 256;                     // NTOK*256 f32
    unsigned short* sh = (unsigned short*)(preln + (size_t)NTOK * 256);
    unsigned short* sl = sh + (size_t)NTOK * 256;
    unsigned short* qh = sl + (size_t)NTOK * 256;
    unsigned short* ql = qh + (size_t)NTOK * 256;
    char* uni = (char*)(ql + (size_t)NTOK * 256);
    unsigned short* valb = (unsigned short*)uni;                        // NTOK*256 u16
    float* oab = (float*)(uni + (size_t)NTOK * 512);                    // NTOK*384 f32
    unsigned short* samp = (unsigned short*)(uni + (size_t)NTOK * 2048);// NTOK*256 u16
    unsigned short* ffnb = (unsigned short*)uni;                        // NTOK*1024 u16
    float* boa640 = (float*)(uni + (size_t)NTOK * 2560);                // 6*640
    unsigned short* Wh = (unsigned short*)(boa640 + 6 * 640);
    const long WL = 753664;                         // per-layer bf16 elems
    unsigned short* Wl = Wh + (size_t)NLAYERS * WL;
    const long O_VAL = 0, O_OFF = 65536, O_ATT = 131072, O_OUT = 163840,
               O_F1 = 229376, O_F2 = 491520;

    // ---- weight prep ----
    wsplit_k<<<dim3(8, 8, 6),  256, 0, stream>>>(w_val,  Wh + O_VAL, Wl + O_VAL, 256, 256,  65536, WL);
    wsplit_k<<<dim3(8, 8, 6),  256, 0, stream>>>(w_off,  Wh + O_OFF, Wl + O_OFF, 256, 256,  65536, WL);
    wsplit_k<<<dim3(4, 8, 6),  256, 0, stream>>>(w_attn, Wh + O_ATT, Wl + O_ATT, 256, 128,  32768, WL);
    wsplit_k<<<dim3(8, 8, 6),  256, 0, stream>>>(w_out,  Wh + O_OUT, Wl + O_OUT, 256, 256,  65536, WL);
    wsplit_k<<<dim3(32, 8, 6), 256, 0, stream>>>(w_ffn1, Wh + O_F1,  Wl + O_F1,  256, 1024, 262144, WL);
    wsplit_k<<<dim3(8, 32, 6), 256, 0, stream>>>(w_ffn2, Wh + O_F2,  Wl + O_F2,  1024, 256, 262144, WL);
    boa_k<<<dim3(6), dim3(640), 0, stream>>>(b_val, b_off, b_attn, boa640);

    const int HWs[4] = {7600, 1900, 475, 130};
    const int STt[4] = {0, 7600, 9500, 9975};
    for (int l = 0; l < 4; ++l) {
        dim3 g((HWs[l] + 63) / 64, 4, BATCH);
        flatten_k<<<g, 256, 0, stream>>>(src_in[l], pos_in[l], lvl + l * 256,
                                         src, pos, sh, sl, qh, ql, HWs[l], STt[l]);
    }

    const int MB = (NTOK + 127) / 128;   // 158
    const int LNB = (NTOK + 3) / 4;      // 5053
    dim3 blk(256);

    for (int i = 0; i < NLAYERS; ++i) {
        const unsigned short* whL = Wh + (size_t)i * WL;
        const unsigned short* wlL = Wl + (size_t)i * WL;
        const float* bou = b_out  + (size_t)i * 256;
        const float* l1g = ln1_g  + (size_t)i * 256;
        const float* l1b = ln1_b  + (size_t)i * 256;
        const float* bf1 = b_ffn1 + (size_t)i * 1024;
        const float* bf2 = b_ffn2 + (size_t)i * 256;
        const float* l2g = ln2_g  + (size_t)i * 256;
        const float* l2b = ln2_b  + (size_t)i * 256;

        // fused [val | off | attn]: N=640
        gemm_top<<<dim3(MB * 5), blk, 0, stream>>>(
            sh, sl, qh, ql, whL, wlL, boa640 + (size_t)i * 640, valb, oab, NTOK);
        // deformable sampling -> samp (bf16)
        sample_k<<<dim3(LQ, BATCH), blk, 0, stream>>>(valb, oab, samp);
        // attn_out = samp @ w_out + b_out + src -> preln
        gemm_std<2, false, true, false><<<dim3(MB * 2), blk, 0, stream>>>(
            samp, nullptr, whL + O_OUT, wlL + O_OUT, bou, src, preln,
            NTOK, 256, 256, 2);
        // LN1 -> src + src planes
        ln_plane_k<false, true><<<dim3(LNB), blk, 0, stream>>>(
            preln, l1g, l1b, nullptr, src, sh, sl, nullptr, nullptr, NTOK);
        // ffn1 = relu(src @ w_ffn1 + b) -> ffnb (bf16), A = src planes
        gemm_std<3, true, false, true><<<dim3(MB * 8), blk, 0, stream>>>(
            sh, sl, whL + O_F1, wlL + O_F1, bf1, nullptr, ffnb,
            NTOK, 1024, 256, 8);
        // ffn2 = ffnb @ w_ffn2 + b + src -> preln
        gemm_std<2, false, true, false><<<dim3(MB * 2), blk, 0, stream>>>(
            ffnb, nullptr, whL + O_F2, wlL + O_F2, bf2, src, preln,
            NTOK, 256, 1024, 2);
        // LN2 -> src + planes + q planes (or d_out on last layer)
        if (i == NLAYERS - 1)
            ln_plane_k<false, false><<<dim3(LNB), blk, 0, stream>>>(
                preln, l2g, l2b, nullptr, (float*)d_out,
                nullptr, nullptr, nullptr, nullptr, NTOK);
        else
            ln_plane_k<true, true><<<dim3(LNB), blk, 0, stream>>>(
                preln, l2g, l2b, pos, src, sh, sl, qh, ql, NTOK);
    }
}

// Round 8
// 1709.498 us; speedup vs baseline: 1.0481x; 1.0053x over previous
//
#include <hip/hip_runtime.h>
#include <math.h>

#define LQ 10105
#define BATCH 2
#define NLAYERS 6
#define NTOK (BATCH * LQ)   // 20210

typedef __attribute__((ext_vector_type(8))) short bf16x8;   // 8 bf16 (4 VGPRs)
typedef __attribute__((ext_vector_type(4))) float f32x4;

__device__ inline unsigned short f2bf_rne(float f) {
    unsigned u = __float_as_uint(f);
    unsigned r = u + 0x7fffu + ((u >> 16) & 1u);
    return (unsigned short)(r >> 16);
}
__device__ inline float bf2f(unsigned short h) {
    return __uint_as_float((unsigned)h << 16);
}
// truncation hi/lo split
__device__ inline void split2(float v, unsigned short& h, unsigned short& l) {
    h = (unsigned short)(__float_as_uint(v) >> 16);
    float r = v - bf2f(h);
    l = (unsigned short)(__float_as_uint(r) >> 16);
}

// counted vmcnt wait (T4): memory clobber pins ds_read/MFMA scheduling
template<int N> __device__ inline void waitcnt_vm() {
    if constexpr (N == 0)      asm volatile("s_waitcnt vmcnt(0)" ::: "memory");
    else if constexpr (N == 6) asm volatile("s_waitcnt vmcnt(6)" ::: "memory");
    else                       asm volatile("s_waitcnt vmcnt(8)" ::: "memory");
}

// async global->LDS staging of one 128x32 bf16 plane, k-slot XOR-swizzled at
// the GLOBAL source (LDS dest stays linear; read side applies same XOR).
__device__ inline void stage_plane(const unsigned short* __restrict__ gp,
                                   unsigned short* lp, int row0, int K, int kt,
                                   int tid)
{
    int rloc = tid >> 2;
    int slot = (tid & 3) ^ ((tid >> 3) & 3);   // involution within 8-row stripe
    int kk   = kt + slot * 8;
    __builtin_amdgcn_global_load_lds(
        (const __attribute__((address_space(1))) void*)(gp + (size_t)(row0 + rloc) * K + kk),
        (__attribute__((address_space(3))) void*)(lp + tid * 8), 16, 0, 0);
    __builtin_amdgcn_global_load_lds(
        (const __attribute__((address_space(1))) void*)(gp + (size_t)(row0 + rloc + 64) * K + kk),
        (__attribute__((address_space(3))) void*)(lp + 2048 + tid * 8), 16, 0, 0);
}

// ---------------------------------------------------------------------------
// Flatten: (B,D,H,W) -> (B,HW,D) with LDS transpose; emits src f32, pos f32,
// src hi/lo planes, q=src+pos hi/lo planes.
// ---------------------------------------------------------------------------
__global__ __launch_bounds__(256)
void flatten_k(const float* __restrict__ src, const float* __restrict__ pos,
               const float* __restrict__ lvl, float* __restrict__ srcf,
               float* __restrict__ posf, unsigned short* __restrict__ sh,
               unsigned short* __restrict__ sl, unsigned short* __restrict__ qh,
               unsigned short* __restrict__ ql, int HW, int start)
{
    __shared__ float ts[64][65], tp[64][65];
    int hw0 = blockIdx.x * 64;
    int d0  = blockIdx.y * 64;
    int b   = blockIdx.z;
    int tid = threadIdx.x;
    int c = tid & 63, rg = tid >> 6;

    #pragma unroll 4
    for (int i = 0; i < 16; ++i) {
        int dl = rg * 16 + i;
        int hw = hw0 + c;
        float s = 0.f, p = 0.f;
        if (hw < HW) {
            s = src[(size_t)(b * 256 + d0 + dl) * HW + hw];
            p = pos[(size_t)(b * 256 + d0 + dl) * HW + hw];
        }
        ts[dl][c] = s;
        tp[dl][c] = p;
    }
    __syncthreads();
    float lv = lvl[d0 + c];
    #pragma unroll 4
    for (int i = 0; i < 16; ++i) {
        int hwl = rg * 16 + i;
        int hw = hw0 + hwl;
        if (hw >= HW) continue;
        float s = ts[c][hwl] + lv;
        float p = tp[c][hwl];
        size_t o = (size_t)(b * LQ + start + hw) * 256 + d0 + c;
        srcf[o] = s;
        posf[o] = p;
        unsigned short h, l;
        split2(s, h, l); sh[o] = h; sl[o] = l;
        float q = s + p;
        split2(q, h, l); qh[o] = h; ql[o] = l;
    }
}

// ---------------------------------------------------------------------------
// Weight transpose + bf16 hi/lo split: W[L][K][N] fp32 -> Th/Tl[L][N][K] bf16
// ---------------------------------------------------------------------------
__global__ __launch_bounds__(256)
void wsplit_k(const float* __restrict__ W, unsigned short* __restrict__ Th,
              unsigned short* __restrict__ Tl, int K, int N,
              long srcStride, long dstStride)
{
    __shared__ float t[32][33];
    int layer = blockIdx.z;
    int n0 = blockIdx.x * 32, k0 = blockIdx.y * 32;
    int tx = threadIdx.x & 31, ty = threadIdx.x >> 5;
    const float* Wsrc = W + (size_t)layer * srcStride;
    #pragma unroll
    for (int i = 0; i < 4; ++i)
        t[ty + i * 8][tx] = Wsrc[(size_t)(k0 + ty + i * 8) * N + n0 + tx];
    __syncthreads();
    unsigned short* th = Th + (size_t)layer * dstStride;
    unsigned short* tl = Tl + (size_t)layer * dstStride;
    #pragma unroll
    for (int i = 0; i < 4; ++i) {
        int n = n0 + ty + i * 8;
        float v = t[tx][ty + i * 8];
        unsigned short h = f2bf_rne(v);
        th[(size_t)n * K + k0 + tx] = h;
        tl[(size_t)n * K + k0 + tx] = f2bf_rne(v - bf2f(h));
    }
}

// combined bias [b_val | b_off | b_attn] -> 640 per layer
__global__ void boa_k(const float* __restrict__ b_val,
                      const float* __restrict__ b_off,
                      const float* __restrict__ b_attn, float* __restrict__ bo)
{
    int l = blockIdx.x, t = threadIdx.x;   // 640 threads
    float v;
    if (t < 256)      v = b_val[l * 256 + t];
    else if (t < 512) v = b_off[l * 256 + (t - 256)];
    else              v = b_attn[l * 128 + (t - 512)];
    bo[l * 640 + t] = v;
}

// ---------------------------------------------------------------------------
// Fused top GEMM: C[:,0:256]=src@w_val -> valb bf16; C[:,256:640]=(q)@[w_off|
// w_attn] -> oab f32. 3-pass split MFMA, dbuf LDS + counted vmcnt (T4).
// ---------------------------------------------------------------------------
__global__ __launch_bounds__(256)
void gemm_top(const unsigned short* __restrict__ Ash,
              const unsigned short* __restrict__ Asl,
              const unsigned short* __restrict__ Aqh,
              const unsigned short* __restrict__ Aql,
              const unsigned short* __restrict__ Bh,
              const unsigned short* __restrict__ Bl,
              const float* __restrict__ bias640,
              unsigned short* __restrict__ valb, float* __restrict__ oab, int M)
{
    constexpr int K = 256, NB = 5;
    __shared__ unsigned short sP[2 * 4 * 4096];  // 2 buf x (Ah|Al|Bh|Bl)

    const int nwg = gridDim.x, bid = blockIdx.x;
    const int q8 = nwg >> 3, r8 = nwg & 7, xcd = bid & 7;
    const int work = (xcd < r8 ? xcd * (q8 + 1) : r8 * (q8 + 1) + (xcd - r8) * q8)
                     + (bid >> 3);
    const int mblk = work / NB;
    const int nb = work - mblk * NB;
    const int m0 = mblk * 128, n0 = nb * 128;

    const unsigned short* Ah = (nb < 2) ? Ash : Aqh;
    const unsigned short* Al = (nb < 2) ? Asl : Aql;

    const int tid = threadIdx.x;
    const int w = tid >> 6, l = tid & 63;
    const int wm = (w >> 1) * 64, wn = (w & 1) * 64;
    const int lr = l & 15, rr = (l >> 4) * 4;
    const int so = (((l >> 4) ^ ((lr >> 1) & 3)) * 8);   // swizzled k-slot

    f32x4 acc[4][4];
    #pragma unroll
    for (int i = 0; i < 4; ++i)
        #pragma unroll
        for (int j = 0; j < 4; ++j) acc[i][j] = (f32x4){0.f, 0.f, 0.f, 0.f};

    auto STAGE = [&](int b, int kt) {   // 8 vm loads per wave
        unsigned short* base = sP + b * 16384;
        stage_plane(Ah, base,         m0, K, kt, tid);
        stage_plane(Al, base + 4096,  m0, K, kt, tid);
        stage_plane(Bh, base + 8192,  n0, K, kt, tid);
        stage_plane(Bl, base + 12288, n0, K, kt, tid);
    };
    auto COMPUTE = [&](int b) {
        unsigned short* base = sP + b * 16384;
        bf16x8 fah[4], fal[4];
        #pragma unroll
        for (int mf = 0; mf < 4; ++mf) {
            int off = (wm + mf * 16 + lr) * 32 + so;
            fah[mf] = *(const bf16x8*)&base[off];
            fal[mf] = *(const bf16x8*)&base[4096 + off];
        }
        #pragma unroll
        for (int nf = 0; nf < 4; ++nf) {
            int boff = (wn + nf * 16 + lr) * 32 + so;
            bf16x8 fbh = *(const bf16x8*)&base[8192 + boff];
            bf16x8 fbl = *(const bf16x8*)&base[12288 + boff];
            #pragma unroll
            for (int mf = 0; mf < 4; ++mf) {
                f32x4 c = acc[mf][nf];
                c = __builtin_amdgcn_mfma_f32_16x16x32_bf16(fah[mf], fbh, c, 0, 0, 0);
                c = __builtin_amdgcn_mfma_f32_16x16x32_bf16(fah[mf], fbl, c, 0, 0, 0);
                c = __builtin_amdgcn_mfma_f32_16x16x32_bf16(fal[mf], fbh, c, 0, 0, 0);
                acc[mf][nf] = c;
            }
        }
    };

    // T4 pipeline: 2 tiles prefetched; waits are counted, never drain mid-loop
    STAGE(0, 0);
    STAGE(1, 32);
    for (int kt = 0; kt < K; kt += 32) {
        int cur = (kt >> 5) & 1;
        if (kt + 32 < K) waitcnt_vm<8>(); else waitcnt_vm<0>();
        __builtin_amdgcn_s_barrier();        // all waves' portions of cur landed
        COMPUTE(cur);
        __builtin_amdgcn_s_barrier();        // all waves done reading cur
        if (kt + 64 < K) STAGE(cur, kt + 64);
    }

    #pragma unroll
    for (int nf = 0; nf < 4; ++nf) {
        int ncol = n0 + wn + nf * 16 + lr;
        float bs = bias640[ncol];
        #pragma unroll
        for (int mf = 0; mf < 4; ++mf) {
            int rowb = m0 + wm + mf * 16 + rr;
            #pragma unroll
            for (int r = 0; r < 4; ++r) {
                int row = rowb + r;
                if (row < M) {
                    float v = acc[mf][nf][r] + bs;
                    if (nb < 2) valb[(size_t)row * 256 + ncol] = f2bf_rne(v);
                    else        oab[(size_t)row * 384 + (ncol - 256)] = v;
                }
            }
        }
    }
}

// ---------------------------------------------------------------------------
// Generic plane GEMM: PASSES=2 (A exact bf16) or 3 (A hi/lo planes).
// Dbuf LDS + counted vmcnt (T4), global_load_lds staging, swizzled reads.
// ---------------------------------------------------------------------------
template<int PASSES, bool RELU, bool HAS_RES, bool C_BF16>
__global__ __launch_bounds__(256)
void gemm_std(const unsigned short* __restrict__ Ah,
              const unsigned short* __restrict__ Al,
              const unsigned short* __restrict__ Bh,
              const unsigned short* __restrict__ Bl,
              const float* __restrict__ bias, const float* __restrict__ Res,
              void* __restrict__ Cv, int M, int N, int K, int NB)
{
    constexpr int NPL = PASSES + 1;
    constexpr int NLOADS = NPL * 2;          // vm loads per wave per STAGE
    __shared__ unsigned short sP[2 * NPL * 4096];

    const int nwg = gridDim.x, bid = blockIdx.x;
    const int q8 = nwg >> 3, r8 = nwg & 7, xcd = bid & 7;
    const int work = (xcd < r8 ? xcd * (q8 + 1) : r8 * (q8 + 1) + (xcd - r8) * q8)
                     + (bid >> 3);
    const int mblk = work / NB;
    const int m0 = mblk * 128;
    const int n0 = (work - mblk * NB) * 128;

    const int tid = threadIdx.x;
    const int w = tid >> 6, l = tid & 63;
    const int wm = (w >> 1) * 64, wn = (w & 1) * 64;
    const int lr = l & 15, rr = (l >> 4) * 4;
    const int so = (((l >> 4) ^ ((lr >> 1) & 3)) * 8);

    f32x4 acc[4][4];
    #pragma unroll
    for (int i = 0; i < 4; ++i)
        #pragma unroll
        for (int j = 0; j < 4; ++j) acc[i][j] = (f32x4){0.f, 0.f, 0.f, 0.f};

    auto STAGE = [&](int b, int kt) {
        unsigned short* base = sP + b * (NPL * 4096);
        stage_plane(Ah, base, m0, K, kt, tid);
        if (PASSES == 3) stage_plane(Al, base + 4096, m0, K, kt, tid);
        stage_plane(Bh, base + (PASSES - 1) * 4096, n0, K, kt, tid);
        stage_plane(Bl, base + PASSES * 4096, n0, K, kt, tid);
    };
    auto COMPUTE = [&](int b) {
        unsigned short* base = sP + b * (NPL * 4096);
        bf16x8 fah[4], fal[4];
        #pragma unroll
        for (int mf = 0; mf < 4; ++mf) {
            int off = (wm + mf * 16 + lr) * 32 + so;
            fah[mf] = *(const bf16x8*)&base[off];
            if (PASSES == 3) fal[mf] = *(const bf16x8*)&base[4096 + off];
        }
        #pragma unroll
        for (int nf = 0; nf < 4; ++nf) {
            int boff = (wn + nf * 16 + lr) * 32 + so;
            bf16x8 fbh = *(const bf16x8*)&base[(PASSES - 1) * 4096 + boff];
            bf16x8 fbl = *(const bf16x8*)&base[PASSES * 4096 + boff];
            #pragma unroll
            for (int mf = 0; mf < 4; ++mf) {
                f32x4 c = acc[mf][nf];
                c = __builtin_amdgcn_mfma_f32_16x16x32_bf16(fah[mf], fbh, c, 0, 0, 0);
                c = __builtin_amdgcn_mfma_f32_16x16x32_bf16(fah[mf], fbl, c, 0, 0, 0);
                if (PASSES == 3)
                    c = __builtin_amdgcn_mfma_f32_16x16x32_bf16(fal[mf], fbh, c, 0, 0, 0);
                acc[mf][nf] = c;
            }
        }
    };

    STAGE(0, 0);
    STAGE(1, 32);
    for (int kt = 0; kt < K; kt += 32) {
        int cur = (kt >> 5) & 1;
        if (kt + 32 < K) waitcnt_vm<NLOADS>(); else waitcnt_vm<0>();
        __builtin_amdgcn_s_barrier();
        COMPUTE(cur);
        __builtin_amdgcn_s_barrier();
        if (kt + 64 < K) STAGE(cur, kt + 64);
    }

    float* Cf = (float*)Cv;
    unsigned short* Cb = (unsigned short*)Cv;
    #pragma unroll
    for (int nf = 0; nf < 4; ++nf) {
        int ncol = n0 + wn + nf * 16 + lr;
        float bs = bias[ncol];
        #pragma unroll
        for (int mf = 0; mf < 4; ++mf) {
            int rowb = m0 + wm + mf * 16 + rr;
            #pragma unroll
            for (int r = 0; r < 4; ++r) {
                int row = rowb + r;
                if (row < M) {
                    float v = acc[mf][nf][r] + bs;
                    if (HAS_RES) v += Res[(size_t)row * N + ncol];
                    if (RELU) v = fmaxf(v, 0.f);
                    if (C_BF16) Cb[(size_t)row * N + ncol] = f2bf_rne(v);
                    else        Cf[(size_t)row * N + ncol] = v;
                }
            }
        }
    }
}

// ---------------------------------------------------------------------------
// Deformable sampling. Block = (q,b), XCD-swizzled q. bf16 val/out.
// ---------------------------------------------------------------------------
__global__ __launch_bounds__(256)
void sample_k(const unsigned short* __restrict__ val,
              const float* __restrict__ oab, unsigned short* __restrict__ out)
{
    const int Hs[4] = {76, 38, 19, 10};
    const int Ws[4] = {100, 50, 25, 13};
    const int ST[4] = {0, 7600, 9500, 9975};

    int bid = blockIdx.x;
    int xcd = bid & 7;
    const int qch = LQ >> 3;
    const int rem = LQ & 7;
    int q = (xcd < rem ? xcd * (qch + 1) : rem * (qch + 1) + (xcd - rem) * qch)
            + (bid >> 3);
    int b = blockIdx.y;
    int tid = threadIdx.x;

    __shared__ int2 s_iw[512];

    if (tid < 128) {
        int h = tid >> 4, pt = tid & 15, lvl = pt >> 2, p = pt & 3;
        int lq, local;
        if (q < 7600)      { lq = 0; local = q; }
        else if (q < 9500) { lq = 1; local = q - 7600; }
        else if (q < 9975) { lq = 2; local = q - 9500; }
        else               { lq = 3; local = q - 9975; }
        int Wq = Ws[lq], Hq = Hs[lq];
        int ry = local / Wq, rx = local - ry * Wq;
        float refx = (rx + 0.5f) / (float)Wq;
        float refy = (ry + 0.5f) / (float)Hq;

        size_t rowb = (size_t)(b * LQ + q) * 384;
        float logit = oab[rowb + 256 + h * 16 + pt];
        float mx = logit;
        mx = fmaxf(mx, __shfl_xor(mx, 1, 64));
        mx = fmaxf(mx, __shfl_xor(mx, 2, 64));
        mx = fmaxf(mx, __shfl_xor(mx, 4, 64));
        mx = fmaxf(mx, __shfl_xor(mx, 8, 64));
        float e = expf(logit - mx);
        float s = e;
        s += __shfl_xor(s, 1, 64);
        s += __shfl_xor(s, 2, 64);
        s += __shfl_xor(s, 4, 64);
        s += __shfl_xor(s, 8, 64);
        float aw = e / s;

        float ox = oab[rowb + h * 32 + lvl * 8 + p * 2];
        float oy = oab[rowb + h * 32 + lvl * 8 + p * 2 + 1];
        int W = Ws[lvl], H = Hs[lvl], st = ST[lvl];
        float px = refx * (float)W + ox - 0.5f;
        float py = refy * (float)H + oy - 0.5f;
        float x0f = floorf(px), y0f = floorf(py);
        float lx = px - x0f, ly = py - y0f;
        int x0 = (int)x0f, y0 = (int)y0f;
        int x1 = x0 + 1, y1 = y0 + 1;
        float ax0 = ((x0 >= 0) & (x0 < W)) ? (1.f - lx) : 0.f;
        float ax1 = ((x1 >= 0) & (x1 < W)) ? lx : 0.f;
        float ay0 = ((y0 >= 0) & (y0 < H)) ? (1.f - ly) : 0.f;
        float ay1 = ((y1 >= 0) & (y1 < H)) ? ly : 0.f;
        int cx0 = min(max(x0, 0), W - 1), cx1 = min(max(x1, 0), W - 1);
        int cy0 = min(max(y0, 0), H - 1), cy1 = min(max(y1, 0), H - 1);
        int i00 = st + cy0 * W + cx0, i01 = st + cy0 * W + cx1;
        int i10 = st + cy1 * W + cx0, i11 = st + cy1 * W + cx1;
        int base4 = tid * 4;
        s_iw[base4 + 0] = make_int2(i00, __float_as_int(aw * ay0 * ax0));
        s_iw[base4 + 1] = make_int2(i01, __float_as_int(aw * ay0 * ax1));
        s_iw[base4 + 2] = make_int2(i10, __float_as_int(aw * ay1 * ax0));
        s_iw[base4 + 3] = make_int2(i11, __float_as_int(aw * ay1 * ax1));
    }
    __syncthreads();

    int lane   = tid & 63;
    int wv     = tid >> 6;
    int h      = wv * 2 + (lane >> 5);
    int half   = lane & 31;
    int corner = half >> 3;
    int c4     = half & 7;
    const unsigned short* vb = val + (size_t)(b * LQ) * 256 + h * 32 + c4 * 4;
    int sbase = h * 64 + corner;

    float4 acc = make_float4(0.f, 0.f, 0.f, 0.f);
    #pragma unroll
    for (int pt = 0; pt < 16; ++pt) {
        int2 iw = s_iw[sbase + pt * 4];
        float wgt = __int_as_float(iw.y);
        ushort4 v = *(const ushort4*)&vb[(size_t)iw.x * 256];
        acc.x += wgt * bf2f(v.x); acc.y += wgt * bf2f(v.y);
        acc.z += wgt * bf2f(v.z); acc.w += wgt * bf2f(v.w);
    }
    acc.x += __shfl_xor(acc.x, 8, 64);  acc.y += __shfl_xor(acc.y, 8, 64);
    acc.z += __shfl_xor(acc.z, 8, 64);  acc.w += __shfl_xor(acc.w, 8, 64);
    acc.x += __shfl_xor(acc.x, 16, 64); acc.y += __shfl_xor(acc.y, 16, 64);
    acc.z += __shfl_xor(acc.z, 16, 64); acc.w += __shfl_xor(acc.w, 16, 64);

    if (corner == 0) {
        ushort4 o;
        o.x = f2bf_rne(acc.x); o.y = f2bf_rne(acc.y);
        o.z = f2bf_rne(acc.z); o.w = f2bf_rne(acc.w);
        *(ushort4*)&out[(size_t)(b * LQ + q) * 256 + h * 32 + c4 * 4] = o;
    }
}

// ---------------------------------------------------------------------------
// LayerNorm D=256 + plane emission. 4 rows/block, one wave/row, float4/lane.
// ---------------------------------------------------------------------------
template<bool EMIT_Q, bool EMIT_PLANES>
__global__ __launch_bounds__(256)
void ln_plane_k(const float* __restrict__ x, const float* __restrict__ g,
                const float* __restrict__ bt, const float* __restrict__ pos,
                float* __restrict__ dst, unsigned short* __restrict__ sh,
                unsigned short* __restrict__ sl, unsigned short* __restrict__ qh,
                unsigned short* __restrict__ ql, int nrows)
{
    int row = blockIdx.x * 4 + (threadIdx.x >> 6);
    int lane = threadIdx.x & 63;
    if (row >= nrows) return;

    float4 v = *(const float4*)&x[(size_t)row * 256 + lane * 4];
    float s = v.x + v.y + v.z + v.w;
    #pragma unroll
    for (int o = 32; o > 0; o >>= 1) s += __shfl_down(s, o, 64);
    s = __shfl(s, 0, 64);
    float m = s * (1.0f / 256.0f);
    float cx = v.x - m, cy = v.y - m, cz = v.z - m, cw = v.w - m;
    float s2 = cx * cx + cy * cy + cz * cz + cw * cw;
    #pragma unroll
    for (int o = 32; o > 0; o >>= 1) s2 += __shfl_down(s2, o, 64);
    s2 = __shfl(s2, 0, 64);
    float rstd = rsqrtf(s2 * (1.0f / 256.0f) + 1e-5f);

    float4 gv = *(const float4*)&g[lane * 4];
    float4 bv = *(const float4*)&bt[lane * 4];
    float4 r;
    r.x = cx * rstd * gv.x + bv.x;
    r.y = cy * rstd * gv.y + bv.y;
    r.z = cz * rstd * gv.z + bv.z;
    r.w = cw * rstd * gv.w + bv.w;
    size_t o4 = (size_t)row * 256 + lane * 4;
    *(float4*)&dst[o4] = r;

    if (EMIT_PLANES) {
        ushort4 hh, ll;
        split2(r.x, hh.x, ll.x); split2(r.y, hh.y, ll.y);
        split2(r.z, hh.z, ll.z); split2(r.w, hh.w, ll.w);
        *(ushort4*)&sh[o4] = hh;
        *(ushort4*)&sl[o4] = ll;
    }
    if (EMIT_Q) {
        float4 pv = *(const float4*)&pos[o4];
        ushort4 hh, ll;
        split2(r.x + pv.x, hh.x, ll.x); split2(r.y + pv.y, hh.y, ll.y);
        split2(r.z + pv.z, hh.z, ll.z); split2(r.w + pv.w, hh.w, ll.w);
        *(ushort4*)&qh[o4] = hh;
        *(ushort4*)&ql[o4] = ll;
    }
}

// ---------------------------------------------------------------------------
extern "C" void kernel_launch(void* const* d_in, const int* in_sizes, int n_in,
                              void* d_out, int out_size, void* d_ws, size_t ws_size,
                              hipStream_t stream)
{
    const float* src_in[4] = {(const float*)d_in[0], (const float*)d_in[2],
                              (const float*)d_in[4], (const float*)d_in[6]};
    const float* pos_in[4] = {(const float*)d_in[1], (const float*)d_in[3],
                              (const float*)d_in[5], (const float*)d_in[7]};
    const float* lvl    = (const float*)d_in[8];
    const float* w_off  = (const float*)d_in[9];
    const float* b_off  = (const float*)d_in[10];
    const float* w_attn = (const float*)d_in[11];
    const float* b_attn = (const float*)d_in[12];
    const float* w_val  = (const float*)d_in[13];
    const float* b_val  = (const float*)d_in[14];
    const float* w_out  = (const float*)d_in[15];
    const float* b_out  = (const float*)d_in[16];
    const float* ln1_g  = (const float*)d_in[17];
    const float* ln1_b  = (const float*)d_in[18];
    const float* w_ffn1 = (const float*)d_in[19];
    const float* b_ffn1 = (const float*)d_in[20];
    const float* w_ffn2 = (const float*)d_in[21];
    const float* b_ffn2 = (const float*)d_in[22];
    const float* ln2_g  = (const float*)d_in[23];
    const float* ln2_b  = (const float*)d_in[24];

    // ---- workspace layout ----
    char* wsb = (char*)d_ws;
    float* src  = (float*)wsb;                                   // NTOK*256 f32
    float* pos  = src + (size_t)NTOK * 256;                      // NTOK*256 f32
    float* preln = pos + (size_t)NTOK * 256;                     // NTOK*256 f32
    unsigned short* sh = (unsigned short*)(preln + (size_t)NTOK * 256);
    unsigned short* sl = sh + (size_t)NTOK * 256;
    unsigned short* qh = sl + (size_t)NTOK * 256;
    unsigned short* ql = qh + (size_t)NTOK * 256;
    char* uni = (char*)(ql + (size_t)NTOK * 256);
    unsigned short* valb = (unsigned short*)uni;                        // NTOK*256 u16
    float* oab = (float*)(uni + (size_t)NTOK * 512);                    // NTOK*384 f32
    unsigned short* samp = (unsigned short*)(uni + (size_t)NTOK * 2048);// NTOK*256 u16
    unsigned short* ffnb = (unsigned short*)uni;                        // NTOK*1024 u16
    float* boa640 = (float*)(uni + (size_t)NTOK * 2560);                // 6*640
    unsigned short* Wh = (unsigned short*)(boa640 + 6 * 640);
    const long WL = 753664;                         // per-layer bf16 elems
    unsigned short* Wl = Wh + (size_t)NLAYERS * WL;
    const long O_VAL = 0, O_OFF = 65536, O_ATT = 131072, O_OUT = 163840,
               O_F1 = 229376, O_F2 = 491520;

    // ---- weight prep ----
    wsplit_k<<<dim3(8, 8, 6),  256, 0, stream>>>(w_val,  Wh + O_VAL, Wl + O_VAL, 256, 256,  65536, WL);
    wsplit_k<<<dim3(8, 8, 6),  256, 0, stream>>>(w_off,  Wh + O_OFF, Wl + O_OFF, 256, 256,  65536, WL);
    wsplit_k<<<dim3(4, 8, 6),  256, 0, stream>>>(w_attn, Wh + O_ATT, Wl + O_ATT, 256, 128,  32768, WL);
    wsplit_k<<<dim3(8, 8, 6),  256, 0, stream>>>(w_out,  Wh + O_OUT, Wl + O_OUT, 256, 256,  65536, WL);
    wsplit_k<<<dim3(32, 8, 6), 256, 0, stream>>>(w_ffn1, Wh + O_F1,  Wl + O_F1,  256, 1024, 262144, WL);
    wsplit_k<<<dim3(8, 32, 6), 256, 0, stream>>>(w_ffn2, Wh + O_F2,  Wl + O_F2,  1024, 256, 262144, WL);
    boa_k<<<dim3(6), dim3(640), 0, stream>>>(b_val, b_off, b_attn, boa640);

    const int HWs[4] = {7600, 1900, 475, 130};
    const int STt[4] = {0, 7600, 9500, 9975};
    for (int l = 0; l < 4; ++l) {
        dim3 g((HWs[l] + 63) / 64, 4, BATCH);
        flatten_k<<<g, 256, 0, stream>>>(src_in[l], pos_in[l], lvl + l * 256,
                                         src, pos, sh, sl, qh, ql, HWs[l], STt[l]);
    }

    const int MB = (NTOK + 127) / 128;   // 158
    const int LNB = (NTOK + 3) / 4;      // 5053
    dim3 blk(256);

    for (int i = 0; i < NLAYERS; ++i) {
        const unsigned short* whL = Wh + (size_t)i * WL;
        const unsigned short* wlL = Wl + (size_t)i * WL;
        const float* bou = b_out  + (size_t)i * 256;
        const float* l1g = ln1_g  + (size_t)i * 256;
        const float* l1b = ln1_b  + (size_t)i * 256;
        const float* bf1 = b_ffn1 + (size_t)i * 1024;
        const float* bf2 = b_ffn2 + (size_t)i * 256;
        const float* l2g = ln2_g  + (size_t)i * 256;
        const float* l2b = ln2_b  + (size_t)i * 256;

        // fused [val | off | attn]: N=640
        gemm_top<<<dim3(MB * 5), blk, 0, stream>>>(
            sh, sl, qh, ql, whL, wlL, boa640 + (size_t)i * 640, valb, oab, NTOK);
        // deformable sampling -> samp (bf16)
        sample_k<<<dim3(LQ, BATCH), blk, 0, stream>>>(valb, oab, samp);
        // attn_out = samp @ w_out + b_out + src -> preln
        gemm_std<2, false, true, false><<<dim3(MB * 2), blk, 0, stream>>>(
            samp, nullptr, whL + O_OUT, wlL + O_OUT, bou, src, preln,
            NTOK, 256, 256, 2);
        // LN1 -> src + src planes
        ln_plane_k<false, true><<<dim3(LNB), blk, 0, stream>>>(
            preln, l1g, l1b, nullptr, src, sh, sl, nullptr, nullptr, NTOK);
        // ffn1 = relu(src @ w_ffn1 + b) -> ffnb (bf16), A = src planes
        gemm_std<3, true, false, true><<<dim3(MB * 8), blk, 0, stream>>>(
            sh, sl, whL + O_F1, wlL + O_F1, bf1, nullptr, ffnb,
            NTOK, 1024, 256, 8);
        // ffn2 = ffnb @ w_ffn2 + b + src -> preln
        gemm_std<2, false, true, false><<<dim3(MB * 2), blk, 0, stream>>>(
            ffnb, nullptr, whL + O_F2, wlL + O_F2, bf2, src, preln,
            NTOK, 256, 1024, 2);
        // LN2 -> src + planes + q planes (or d_out on last layer)
        if (i == NLAYERS - 1)
            ln_plane_k<false, false><<<dim3(LNB), blk, 0, stream>>>(
                preln, l2g, l2b, nullptr, (float*)d_out,
                nullptr, nullptr, nullptr, nullptr, NTOK);
        else
            ln_plane_k<true, true><<<dim3(LNB), blk, 0, stream>>>(
                preln, l2g, l2b, pos, src, sh, sl, qh, ql, NTOK);
    }
}